// Round 3
// baseline (592.762 us; speedup 1.0000x reference)
//
#include <hip/hip_runtime.h>
#include <stdint.h>

#define EMB 2048
#define NH 16
#define QRANK 1536
#define KVRANK 512
#define ROPED 64
#define NOPED 64
#define VD 128
#define QKD 128
#define SEQ 2048
#define BATCH 2
#define BS 4096            // BATCH*SEQ
#define BHD 32             // BATCH*NH
#define NCOMB 2112         // QRANK + KVRANK + ROPED

typedef __attribute__((ext_vector_type(4))) float f32x4;
typedef __attribute__((ext_vector_type(8))) short s16x8;

__device__ __forceinline__ float bf2f(unsigned short u) {
  return __uint_as_float(((unsigned int)u) << 16);
}
__device__ __forceinline__ unsigned short f2bf(float f) {
  unsigned int u = __float_as_uint(f);
  u += 0x7fff + ((u >> 16) & 1);
  return (unsigned short)(u >> 16);
}

__device__ __forceinline__ void gld_lds16(const unsigned short* g, unsigned short* l) {
  __builtin_amdgcn_global_load_lds((const __attribute__((address_space(1))) void*)g,
                                   (__attribute__((address_space(3))) void*)l,
                                   16, 0, 0);
}

// ---------------- fused cast f32 -> bf16, all 6 tensors, one launch ----------
#define N4_X   (BS * EMB / 4)                    // 2097152
#define N4_QA  (QRANK * EMB / 4)                 // 786432
#define N4_KVA ((KVRANK + ROPED) * EMB / 4)      // 294912
#define N4_QB  (NH * QKD * QRANK / 4)            // 786432
#define N4_KVB (NH * 192 * KVRANK / 4)           // 393216
#define N4_O   (EMB * NH * VD / 4)               // 1048576
#define N4_TOT (N4_X + N4_QA + N4_KVA + N4_QB + N4_KVB + N4_O)

__global__ void cast_all(const float* __restrict__ x, const float* __restrict__ qa,
                         const float* __restrict__ kva, const float* __restrict__ qb,
                         const float* __restrict__ kvb, const float* __restrict__ ow,
                         unsigned short* __restrict__ Xb, unsigned short* __restrict__ Wcomb,
                         unsigned short* __restrict__ Wqb, unsigned short* __restrict__ Wkvb,
                         unsigned short* __restrict__ Wo) {
  int i = blockIdx.x * blockDim.x + threadIdx.x;
  int stride = gridDim.x * blockDim.x;
  for (; i < N4_TOT; i += stride) {
    const float4* src;
    ushort4* dst;
    int j = i;
    if (j < N4_X) { src = (const float4*)x; dst = (ushort4*)Xb; }
    else if ((j -= N4_X) < N4_QA) { src = (const float4*)qa; dst = (ushort4*)Wcomb; }
    else if ((j -= N4_QA) < N4_KVA) { src = (const float4*)kva; dst = (ushort4*)(Wcomb + (size_t)QRANK * EMB); }
    else if ((j -= N4_KVA) < N4_QB) { src = (const float4*)qb; dst = (ushort4*)Wqb; }
    else if ((j -= N4_QB) < N4_KVB) { src = (const float4*)kvb; dst = (ushort4*)Wkvb; }
    else { j -= N4_KVB; src = (const float4*)ow; dst = (ushort4*)Wo; }
    float4 v = src[j];
    ushort4 o;
    o.x = f2bf(v.x); o.y = f2bf(v.y); o.z = f2bf(v.z); o.w = f2bf(v.w);
    dst[j] = o;
  }
}

// ---------------- GEMM: C[M,N] = A[M,K(lda)] * W[N,K(ldw)]^T ----------------
// 128x128 tile, BK=64, 4 waves 2x2, each wave 64x64. 16B-chunk XOR swizzle.
template <int OUT_F32>
__global__ __launch_bounds__(256, 2) void gemm_bt(
    const unsigned short* __restrict__ A, int lda,
    const unsigned short* __restrict__ W, int ldw,
    void* __restrict__ C, int M, int N, int K)
{
  __shared__ __align__(16) unsigned short As[128 * 64];
  __shared__ __align__(16) unsigned short Ws[128 * 64];
  const int tid = threadIdx.x;
  const int wave = tid >> 6;
  const int lane = tid & 63;
  const int ln = lane & 15;
  const int quad = lane >> 4;
  const int bm = blockIdx.y * 128;
  const int bn = blockIdx.x * 128;
  const int wm = (wave >> 1) * 64;
  const int wn = (wave & 1) * 64;

  f32x4 acc[4][4] = {};

  const int rel8 = lane >> 3;
  const int csw = ((lane & 7) ^ rel8) * 8;

  for (int k0 = 0; k0 < K; k0 += 64) {
#pragma unroll
    for (int it = 0; it < 4; ++it) {
      int rb = wave * 32 + it * 8;
      gld_lds16(A + (size_t)(bm + rb + rel8) * lda + k0 + csw, &As[rb * 64]);
    }
#pragma unroll
    for (int it = 0; it < 4; ++it) {
      int rb = wave * 32 + it * 8;
      int wr = bn + rb + rel8;
      if (wr >= N) wr = N - 1;
      gld_lds16(W + (size_t)wr * ldw + k0 + csw, &Ws[rb * 64]);
    }
    __syncthreads();
#pragma unroll
    for (int kk = 0; kk < 64; kk += 32) {
      s16x8 a[4], b[4];
#pragma unroll
      for (int mt = 0; mt < 4; ++mt)
        a[mt] = *(const s16x8*)&As[(wm + mt * 16 + ln) * 64 + ((kk / 8 + quad) ^ (ln & 7)) * 8];
#pragma unroll
      for (int nt = 0; nt < 4; ++nt)
        b[nt] = *(const s16x8*)&Ws[(wn + nt * 16 + ln) * 64 + ((kk / 8 + quad) ^ (ln & 7)) * 8];
#pragma unroll
      for (int mt = 0; mt < 4; ++mt)
#pragma unroll
        for (int nt = 0; nt < 4; ++nt)
          acc[mt][nt] = __builtin_amdgcn_mfma_f32_16x16x32_bf16(a[mt], b[nt], acc[mt][nt], 0, 0, 0);
    }
    __syncthreads();
  }
#pragma unroll
  for (int mt = 0; mt < 4; ++mt) {
    int row = bm + wm + mt * 16 + quad * 4;
#pragma unroll
    for (int nt = 0; nt < 4; ++nt) {
      int col = bn + wn + nt * 16 + ln;
      if (col < N) {
#pragma unroll
        for (int r = 0; r < 4; ++r) {
          float v = acc[mt][nt][r];
          if (OUT_F32)
            ((float*)C)[(size_t)(row + r) * N + col] = v;
          else
            ((unsigned short*)C)[(size_t)(row + r) * N + col] = f2bf(v);
        }
      }
    }
  }
}

// ---------------- q GEMM with fused RoPE + (B,H,S,128) permuted store --------
// C row = bs index, col = h*128+d. d>=64 gets interleaved RoPE (pair via shfl).
__global__ __launch_bounds__(256, 2) void gemm_q_rope(
    const unsigned short* __restrict__ A, int lda,
    const unsigned short* __restrict__ W, int ldw,
    unsigned short* __restrict__ Qry, int K)
{
  __shared__ __align__(16) unsigned short As[128 * 64];
  __shared__ __align__(16) unsigned short Ws[128 * 64];
  const int tid = threadIdx.x;
  const int wave = tid >> 6;
  const int lane = tid & 63;
  const int ln = lane & 15;
  const int quad = lane >> 4;
  const int bm = blockIdx.y * 128;
  const int bn = blockIdx.x * 128;
  const int wm = (wave >> 1) * 64;
  const int wn = (wave & 1) * 64;

  f32x4 acc[4][4] = {};
  const int rel8 = lane >> 3;
  const int csw = ((lane & 7) ^ rel8) * 8;

  for (int k0 = 0; k0 < K; k0 += 64) {
#pragma unroll
    for (int it = 0; it < 4; ++it) {
      int rb = wave * 32 + it * 8;
      gld_lds16(A + (size_t)(bm + rb + rel8) * lda + k0 + csw, &As[rb * 64]);
    }
#pragma unroll
    for (int it = 0; it < 4; ++it) {
      int rb = wave * 32 + it * 8;
      gld_lds16(W + (size_t)(bn + rb + rel8) * ldw + k0 + csw, &Ws[rb * 64]);
    }
    __syncthreads();
#pragma unroll
    for (int kk = 0; kk < 64; kk += 32) {
      s16x8 a[4], b[4];
#pragma unroll
      for (int mt = 0; mt < 4; ++mt)
        a[mt] = *(const s16x8*)&As[(wm + mt * 16 + ln) * 64 + ((kk / 8 + quad) ^ (ln & 7)) * 8];
#pragma unroll
      for (int nt = 0; nt < 4; ++nt)
        b[nt] = *(const s16x8*)&Ws[(wn + nt * 16 + ln) * 64 + ((kk / 8 + quad) ^ (ln & 7)) * 8];
#pragma unroll
      for (int mt = 0; mt < 4; ++mt)
#pragma unroll
        for (int nt = 0; nt < 4; ++nt)
          acc[mt][nt] = __builtin_amdgcn_mfma_f32_16x16x32_bf16(a[mt], b[nt], acc[mt][nt], 0, 0, 0);
    }
    __syncthreads();
  }
  const bool odd = (ln & 1);
#pragma unroll
  for (int mt = 0; mt < 4; ++mt) {
    int rowb = bm + wm + mt * 16 + quad * 4;
#pragma unroll
    for (int nt = 0; nt < 4; ++nt) {
      int col = bn + wn + nt * 16 + ln;
      int h = col >> 7, d = col & 127;
#pragma unroll
      for (int r = 0; r < 4; ++r) {
        float v = acc[mt][nt][r];
        float other = __shfl_xor(v, 1);
        int row = rowb + r;
        int b = row >> 11, s = row & 2047;
        float y = v;
        if (d >= NOPED) {   // uniform per 16-lane group
          int i = (d - NOPED) >> 1;
          float theta = exp2f(-(float)i * (13.287712379549449f / 32.f));
          float ang = (float)s * theta;
          float sn, c;
          sincosf(ang, &sn, &c);
          y = v * c + (odd ? other * sn : -other * sn);
        }
        Qry[((size_t)(b * NH + h) * SEQ + s) * QKD + d] = f2bf(y);
      }
    }
  }
}

// ---------------- prep K: kvb nope + RoPE(cqkv rope cols) -> (B,H,S,128) -----
__global__ void prep_key(const unsigned short* __restrict__ kvb,
                         const unsigned short* __restrict__ cqkv,
                         unsigned short* __restrict__ Key) {
  __shared__ unsigned short krot[ROPED];
  int bs = blockIdx.x;
  int b = bs >> 11, s = bs & 2047;
  int tid = threadIdx.x;
  if (tid < 32) {
    int i = tid;
    float x0 = bf2f(cqkv[(size_t)bs * NCOMB + QRANK + KVRANK + 2 * i]);
    float x1 = bf2f(cqkv[(size_t)bs * NCOMB + QRANK + KVRANK + 2 * i + 1]);
    float theta = exp2f(-(float)i * (13.287712379549449f / 32.f));
    float ang = (float)s * theta;
    float sn, c;
    sincosf(ang, &sn, &c);
    krot[2 * i] = f2bf(x0 * c - x1 * sn);
    krot[2 * i + 1] = f2bf(x1 * c + x0 * sn);
  }
  __syncthreads();
  for (int idx = tid; idx < NH * QKD; idx += 256) {
    int h = idx >> 7, d = idx & 127;
    unsigned short v;
    if (d < NOPED)
      v = kvb[(size_t)bs * (NH * 192) + h * 192 + d];
    else
      v = krot[d - NOPED];
    Key[((size_t)(b * NH + h) * SEQ + s) * QKD + d] = v;
  }
}

// ---------------- transpose V: kvb[...,64:192] -> VT (B,H,128,S) ----------------
__global__ void transpose_v(const unsigned short* __restrict__ kvb, unsigned short* __restrict__ VT) {
  __shared__ unsigned short tile[64][132];
  int blk = blockIdx.x;
  int bh = blk >> 5, st = blk & 31;
  int b = bh >> 4, h = bh & 15;
  int s0 = st * 64;
  int tid = threadIdx.x;
  for (int idx = tid; idx < 64 * 128; idx += 256) {
    int sl = idx >> 7, d = idx & 127;
    tile[sl][d] = kvb[((size_t)(b * SEQ + s0 + sl)) * (NH * 192) + h * 192 + NOPED + d];
  }
  __syncthreads();
  for (int idx = tid; idx < 64 * 128; idx += 256) {
    int d = idx >> 6, sl = idx & 63;
    VT[((size_t)bh * VD + d) * SEQ + s0 + sl] = tile[sl][d];
  }
}

// ---------------- flash attention v3: Q direct to regs, 48KB LDS, 3 blk/CU ---
// Q,K: (BH, S, 128); VT: (BH, 128, S); O: (B, S, H*128) bf16.
__global__ __launch_bounds__(256, 3) void flash_attn(
    const unsigned short* __restrict__ Q,
    const unsigned short* __restrict__ Kt,
    const unsigned short* __restrict__ VT,
    unsigned short* __restrict__ O)
{
  __shared__ __align__(16) unsigned short Ks[64 * 128];
  __shared__ __align__(16) unsigned short Vs[128 * 64];
  __shared__ __align__(16) unsigned short Ps[4 * 2048];

  const int tid = threadIdx.x;
  const int wave = tid >> 6;
  const int lane = tid & 63;
  const int ln = lane & 15;
  const int quad = lane >> 4;
  const int bh = blockIdx.x;
  const int q0 = blockIdx.y * 128;

  // ---- Q a-frags straight from global (rows wave*32+mt*16+ln, k = kx*32+quad*8)
  s16x8 qa[2][4];
#pragma unroll
  for (int mt = 0; mt < 2; ++mt) {
    const unsigned short* qrow = Q + ((size_t)bh * SEQ + q0 + wave * 32 + mt * 16 + ln) * QKD;
#pragma unroll
    for (int kx = 0; kx < 4; ++kx)
      qa[mt][kx] = *(const s16x8*)(qrow + kx * 32 + quad * 8);
  }

  unsigned short* Pw = &Ps[wave * 2048];  // 32 rows x 64 cols, row-pair swizzled

  f32x4 o[2][8] = {};
  float m_i[2][4], l_i[2][4];
#pragma unroll
  for (int mt = 0; mt < 2; ++mt)
#pragma unroll
    for (int r = 0; r < 4; ++r) { m_i[mt][r] = -1e30f; l_i[mt][r] = 0.f; }

  const bool even = ((ln & 1) == 0);

  for (int kt = 0; kt < SEQ / 64; ++kt) {
    // stage K (64x128, 16-chunk swizzle) and V^T (128x64, 8-chunk swizzle)
    {
      int rel = lane >> 4, cch = lane & 15;
#pragma unroll
      for (int it = 0; it < 4; ++it) {
        int rb = wave * 16 + it * 4;
        int rr = rb + rel;
        int c = cch ^ (rr & 15);
        gld_lds16(Kt + ((size_t)bh * SEQ + kt * 64 + rr) * QKD + c * 8, &Ks[rb * 128]);
      }
      int rel8 = lane >> 3;
      int c8 = (lane & 7) ^ rel8;
#pragma unroll
      for (int it = 0; it < 4; ++it) {
        int rb = wave * 32 + it * 8;
        gld_lds16(VT + ((size_t)bh * VD + rb + rel8) * SEQ + kt * 64 + c8 * 8, &Vs[rb * 64]);
      }
    }
    __syncthreads();

    // ---- S = Q K^T (32q x 64k per wave)
    f32x4 sc[2][4] = {};
#pragma unroll
    for (int kx = 0; kx < 4; ++kx) {
      s16x8 bk[4];
#pragma unroll
      for (int t = 0; t < 4; ++t)
        bk[t] = *(const s16x8*)&Ks[(t * 16 + ln) * 128 + ((kx * 4 + quad) ^ ln) * 8];
#pragma unroll
      for (int mt = 0; mt < 2; ++mt)
#pragma unroll
        for (int t = 0; t < 4; ++t)
          sc[mt][t] = __builtin_amdgcn_mfma_f32_16x16x32_bf16(qa[mt][kx], bk[t], sc[mt][t], 0, 0, 0);
    }

    // ---- online softmax per (mt, r); row = mt*16 + quad*4 + r
    float al[2][4];
#pragma unroll
    for (int mt = 0; mt < 2; ++mt) {
      float mx[4], rs[4];
#pragma unroll
      for (int r = 0; r < 4; ++r)
        mx[r] = fmaxf(fmaxf(sc[mt][0][r], sc[mt][1][r]), fmaxf(sc[mt][2][r], sc[mt][3][r]));
#pragma unroll
      for (int msk = 1; msk < 16; msk <<= 1)
#pragma unroll
        for (int r = 0; r < 4; ++r)
          mx[r] = fmaxf(mx[r], __shfl_xor(mx[r], msk));
#pragma unroll
      for (int r = 0; r < 4; ++r) {
        float mn = fmaxf(m_i[mt][r], mx[r]);
        al[mt][r] = __expf(m_i[mt][r] - mn);
        m_i[mt][r] = mn;
        rs[r] = 0.f;
      }
#pragma unroll
      for (int t = 0; t < 4; ++t)
#pragma unroll
        for (int r = 0; r < 4; ++r) {
          float e = __expf(sc[mt][t][r] - m_i[mt][r]);
          sc[mt][t][r] = e;
          rs[r] += e;
        }
#pragma unroll
      for (int msk = 1; msk < 16; msk <<= 1)
#pragma unroll
        for (int r = 0; r < 4; ++r)
          rs[r] += __shfl_xor(rs[r], msk);
#pragma unroll
      for (int r = 0; r < 4; ++r)
        l_i[mt][r] = l_i[mt][r] * al[mt][r] + rs[r];
#pragma unroll
      for (int dt = 0; dt < 8; ++dt)
#pragma unroll
        for (int r = 0; r < 4; ++r)
          o[mt][dt][r] *= al[mt][r];
    }

    // ---- P -> LDS (pack pairs via shfl, dword writes by even lanes)
#pragma unroll
    for (int mt = 0; mt < 2; ++mt)
#pragma unroll
      for (int t = 0; t < 4; ++t) {
        unsigned int pu[4], nu[4];
#pragma unroll
        for (int r = 0; r < 4; ++r) {
          pu[r] = __float_as_uint(sc[mt][t][r]);
          nu[r] = __float_as_uint(__shfl_xor(sc[mt][t][r], 1));
        }
        if (even) {
          int cb = t * 2 + (ln >> 3);
          int rbase = mt * 16 + quad * 4;
#pragma unroll
          for (int rp = 0; rp < 2; ++rp) {
            int swc = cb ^ (quad * 2 + rp);
            unsigned short* a = &Pw[(rbase + 2 * rp) * 64 + swc * 8 + (ln & 7)];
            *(unsigned int*)a        = (pu[2 * rp] >> 16)     | (nu[2 * rp] & 0xffff0000u);
            *(unsigned int*)(a + 64) = (pu[2 * rp + 1] >> 16) | (nu[2 * rp + 1] & 0xffff0000u);
          }
        }
      }
    asm volatile("s_waitcnt lgkmcnt(0)" ::: "memory");

    // ---- O += P @ V
#pragma unroll
    for (int kc = 0; kc < 2; ++kc) {
      s16x8 ap[2];
#pragma unroll
      for (int mt = 0; mt < 2; ++mt)
        ap[mt] = *(const s16x8*)&Pw[(mt * 16 + ln) * 64 + ((kc * 4 + quad) ^ (ln >> 1)) * 8];
#pragma unroll
      for (int dt = 0; dt < 8; ++dt) {
        s16x8 bv = *(const s16x8*)&Vs[(dt * 16 + ln) * 64 + ((kc * 4 + quad) ^ (ln & 7)) * 8];
#pragma unroll
        for (int mt = 0; mt < 2; ++mt)
          o[mt][dt] = __builtin_amdgcn_mfma_f32_16x16x32_bf16(ap[mt], bv, o[mt][dt], 0, 0, 0);
      }
    }
    __syncthreads();
  }

  const int b = bh >> 4, h = bh & 15;
#pragma unroll
  for (int mt = 0; mt < 2; ++mt)
#pragma unroll
    for (int r = 0; r < 4; ++r) {
      float inv = 1.f / l_i[mt][r];
      int s = q0 + wave * 32 + mt * 16 + quad * 4 + r;
      size_t rowbase = ((size_t)b * SEQ + s) * (NH * VD) + h * VD;
#pragma unroll
      for (int dt = 0; dt < 8; ++dt)
        O[rowbase + dt * 16 + ln] = f2bf(o[mt][dt][r] * inv);
    }
}

extern "C" void kernel_launch(void* const* d_in, const int* in_sizes, int n_in,
                              void* d_out, int out_size, void* d_ws, size_t ws_size,
                              hipStream_t stream) {
  const float* x_f    = (const float*)d_in[0];
  const float* qaw_f  = (const float*)d_in[1];
  const float* qbw_f  = (const float*)d_in[2];
  const float* kvaw_f = (const float*)d_in[3];
  const float* kvbw_f = (const float*)d_in[4];
  const float* ow_f   = (const float*)d_in[5];

  char* ws = (char*)d_ws;
  size_t off = 0;
  auto alloc = [&](size_t n) {
    unsigned short* p = (unsigned short*)(ws + off);
    off = (off + n * 2 + 255) & ~(size_t)255;
    return p;
  };
  unsigned short* Xb    = alloc((size_t)BS * EMB);
  unsigned short* Wcomb = alloc((size_t)NCOMB * EMB);            // qa rows then kva rows
  unsigned short* Wqb   = alloc((size_t)(NH * QKD) * QRANK);
  unsigned short* Wkvb  = alloc((size_t)(NH * 192) * KVRANK);
  unsigned short* Wo    = alloc((size_t)EMB * (NH * VD));
  unsigned short* CQKV  = alloc((size_t)BS * NCOMB);             // cq | ckv | rope
  unsigned short* KVB   = alloc((size_t)BS * (NH * 192));
  unsigned short* Qry   = alloc((size_t)BHD * SEQ * QKD);
  unsigned short* Key   = alloc((size_t)BHD * SEQ * QKD);
  unsigned short* Vt    = alloc((size_t)BHD * VD * SEQ);
  unsigned short* AO    = alloc((size_t)BS * (NH * VD));

  cast_all<<<dim3(8192), 256, 0, stream>>>(x_f, qaw_f, kvaw_f, qbw_f, kvbw_f, ow_f,
                                           Xb, Wcomb, Wqb, Wkvb, Wo);

  // [cq | ckv] = x @ [q_a_w; kv_a_w]^T  (4096 x 2112, K=2048)
  gemm_bt<0><<<dim3((NCOMB + 127) / 128, BS / 128), 256, 0, stream>>>(
      Xb, EMB, Wcomb, EMB, CQKV, BS, NCOMB, EMB);
  // q = cq @ q_b_w^T with fused RoPE + permuted store (4096 x 2048, K=1536)
  gemm_q_rope<<<dim3((NH * QKD) / 128, BS / 128), 256, 0, stream>>>(
      CQKV, NCOMB, Wqb, QRANK, Qry, QRANK);
  // kvb = ckv @ kv_b_w^T (4096 x 3072, K=512)
  gemm_bt<0><<<dim3((NH * 192) / 128, BS / 128), 256, 0, stream>>>(
      CQKV + QRANK, NCOMB, Wkvb, KVRANK, KVB, BS, NH * 192, KVRANK);

  prep_key<<<dim3(BS), 256, 0, stream>>>(KVB, CQKV, Key);
  transpose_v<<<dim3(BHD * (SEQ / 64)), 256, 0, stream>>>(KVB, Vt);

  flash_attn<<<dim3(BHD, SEQ / 128), 256, 0, stream>>>(Qry, Key, Vt, AO);

  // out = AO @ o_w^T (fp32 out)
  gemm_bt<1><<<dim3(EMB / 128, BS / 128), 256, 0, stream>>>(
      AO, NH * VD, Wo, NH * VD, d_out, BS, EMB, NH * VD);
}

// Round 4
// 433.440 us; speedup vs baseline: 1.3676x; 1.3676x over previous
//
#include <hip/hip_runtime.h>
#include <stdint.h>

#define EMB 2048
#define NH 16
#define QRANK 1536
#define KVRANK 512
#define ROPED 64
#define NOPED 64
#define VD 128
#define QKD 128
#define SEQ 2048
#define BATCH 2
#define BS 4096            // BATCH*SEQ
#define BHD 32             // BATCH*NH
#define NCOMB 2112         // QRANK + KVRANK + ROPED

typedef __attribute__((ext_vector_type(4))) float f32x4;
typedef __attribute__((ext_vector_type(8))) short s16x8;

__device__ __forceinline__ float bf2f(unsigned short u) {
  return __uint_as_float(((unsigned int)u) << 16);
}
__device__ __forceinline__ unsigned short f2bf(float f) {
  unsigned int u = __float_as_uint(f);
  u += 0x7fff + ((u >> 16) & 1);
  return (unsigned short)(u >> 16);
}

__device__ __forceinline__ void gld_lds16(const unsigned short* g, unsigned short* l) {
  __builtin_amdgcn_global_load_lds((const __attribute__((address_space(1))) void*)g,
                                   (__attribute__((address_space(3))) void*)l,
                                   16, 0, 0);
}

// ---------------- fused cast f32 -> bf16, all 6 tensors, one launch ----------
#define N4_X   (BS * EMB / 4)
#define N4_QA  (QRANK * EMB / 4)
#define N4_KVA ((KVRANK + ROPED) * EMB / 4)
#define N4_QB  (NH * QKD * QRANK / 4)
#define N4_KVB (NH * 192 * KVRANK / 4)
#define N4_O   (EMB * NH * VD / 4)
#define N4_TOT (N4_X + N4_QA + N4_KVA + N4_QB + N4_KVB + N4_O)

__global__ void cast_all(const float* __restrict__ x, const float* __restrict__ qa,
                         const float* __restrict__ kva, const float* __restrict__ qb,
                         const float* __restrict__ kvb, const float* __restrict__ ow,
                         unsigned short* __restrict__ Xb, unsigned short* __restrict__ Wcomb,
                         unsigned short* __restrict__ Wqb, unsigned short* __restrict__ Wkvb,
                         unsigned short* __restrict__ Wo) {
  int i = blockIdx.x * blockDim.x + threadIdx.x;
  int stride = gridDim.x * blockDim.x;
  for (; i < N4_TOT; i += stride) {
    const float4* src;
    ushort4* dst;
    int j = i;
    if (j < N4_X) { src = (const float4*)x; dst = (ushort4*)Xb; }
    else if ((j -= N4_X) < N4_QA) { src = (const float4*)qa; dst = (ushort4*)Wcomb; }
    else if ((j -= N4_QA) < N4_KVA) { src = (const float4*)kva; dst = (ushort4*)(Wcomb + (size_t)QRANK * EMB); }
    else if ((j -= N4_KVA) < N4_QB) { src = (const float4*)qb; dst = (ushort4*)Wqb; }
    else if ((j -= N4_QB) < N4_KVB) { src = (const float4*)kvb; dst = (ushort4*)Wkvb; }
    else { j -= N4_KVB; src = (const float4*)ow; dst = (ushort4*)Wo; }
    float4 v = src[j];
    ushort4 o;
    o.x = f2bf(v.x); o.y = f2bf(v.y); o.z = f2bf(v.z); o.w = f2bf(v.w);
    dst[j] = o;
  }
}

// ---------------- GEMM: C[M,N] = A[M,K(lda)] * W[N,K(ldw)]^T ----------------
// 128x128 tile, BK=64, 4 waves 2x2, each wave 64x64. 16B-chunk XOR swizzle.
template <int OUT_F32>
__global__ __launch_bounds__(256, 2) void gemm_bt(
    const unsigned short* __restrict__ A, int lda,
    const unsigned short* __restrict__ W, int ldw,
    void* __restrict__ C, int M, int N, int K)
{
  __shared__ __align__(16) unsigned short As[128 * 64];
  __shared__ __align__(16) unsigned short Ws[128 * 64];
  const int tid = threadIdx.x;
  const int wave = tid >> 6;
  const int lane = tid & 63;
  const int ln = lane & 15;
  const int quad = lane >> 4;
  const int bm = blockIdx.y * 128;
  const int bn = blockIdx.x * 128;
  const int wm = (wave >> 1) * 64;
  const int wn = (wave & 1) * 64;

  f32x4 acc[4][4] = {};

  const int rel8 = lane >> 3;
  const int csw = ((lane & 7) ^ rel8) * 8;

  for (int k0 = 0; k0 < K; k0 += 64) {
#pragma unroll
    for (int it = 0; it < 4; ++it) {
      int rb = wave * 32 + it * 8;
      gld_lds16(A + (size_t)(bm + rb + rel8) * lda + k0 + csw, &As[rb * 64]);
    }
#pragma unroll
    for (int it = 0; it < 4; ++it) {
      int rb = wave * 32 + it * 8;
      int wr = bn + rb + rel8;
      if (wr >= N) wr = N - 1;
      gld_lds16(W + (size_t)wr * ldw + k0 + csw, &Ws[rb * 64]);
    }
    __syncthreads();
#pragma unroll
    for (int kk = 0; kk < 64; kk += 32) {
      s16x8 a[4], b[4];
#pragma unroll
      for (int mt = 0; mt < 4; ++mt)
        a[mt] = *(const s16x8*)&As[(wm + mt * 16 + ln) * 64 + ((kk / 8 + quad) ^ (ln & 7)) * 8];
#pragma unroll
      for (int nt = 0; nt < 4; ++nt)
        b[nt] = *(const s16x8*)&Ws[(wn + nt * 16 + ln) * 64 + ((kk / 8 + quad) ^ (ln & 7)) * 8];
#pragma unroll
      for (int mt = 0; mt < 4; ++mt)
#pragma unroll
        for (int nt = 0; nt < 4; ++nt)
          acc[mt][nt] = __builtin_amdgcn_mfma_f32_16x16x32_bf16(a[mt], b[nt], acc[mt][nt], 0, 0, 0);
    }
    __syncthreads();
  }
#pragma unroll
  for (int mt = 0; mt < 4; ++mt) {
    int row = bm + wm + mt * 16 + quad * 4;
#pragma unroll
    for (int nt = 0; nt < 4; ++nt) {
      int col = bn + wn + nt * 16 + ln;
      if (col < N) {
#pragma unroll
        for (int r = 0; r < 4; ++r) {
          float v = acc[mt][nt][r];
          if (OUT_F32)
            ((float*)C)[(size_t)(row + r) * N + col] = v;
          else
            ((unsigned short*)C)[(size_t)(row + r) * N + col] = f2bf(v);
        }
      }
    }
  }
}

// ---------------- q GEMM with fused RoPE + (B,H,S,128) permuted store --------
__global__ __launch_bounds__(256, 2) void gemm_q_rope(
    const unsigned short* __restrict__ A, int lda,
    const unsigned short* __restrict__ W, int ldw,
    unsigned short* __restrict__ Qry, int K)
{
  __shared__ __align__(16) unsigned short As[128 * 64];
  __shared__ __align__(16) unsigned short Ws[128 * 64];
  const int tid = threadIdx.x;
  const int wave = tid >> 6;
  const int lane = tid & 63;
  const int ln = lane & 15;
  const int quad = lane >> 4;
  const int bm = blockIdx.y * 128;
  const int bn = blockIdx.x * 128;
  const int wm = (wave >> 1) * 64;
  const int wn = (wave & 1) * 64;

  f32x4 acc[4][4] = {};
  const int rel8 = lane >> 3;
  const int csw = ((lane & 7) ^ rel8) * 8;

  for (int k0 = 0; k0 < K; k0 += 64) {
#pragma unroll
    for (int it = 0; it < 4; ++it) {
      int rb = wave * 32 + it * 8;
      gld_lds16(A + (size_t)(bm + rb + rel8) * lda + k0 + csw, &As[rb * 64]);
    }
#pragma unroll
    for (int it = 0; it < 4; ++it) {
      int rb = wave * 32 + it * 8;
      gld_lds16(W + (size_t)(bn + rb + rel8) * ldw + k0 + csw, &Ws[rb * 64]);
    }
    __syncthreads();
#pragma unroll
    for (int kk = 0; kk < 64; kk += 32) {
      s16x8 a[4], b[4];
#pragma unroll
      for (int mt = 0; mt < 4; ++mt)
        a[mt] = *(const s16x8*)&As[(wm + mt * 16 + ln) * 64 + ((kk / 8 + quad) ^ (ln & 7)) * 8];
#pragma unroll
      for (int nt = 0; nt < 4; ++nt)
        b[nt] = *(const s16x8*)&Ws[(wn + nt * 16 + ln) * 64 + ((kk / 8 + quad) ^ (ln & 7)) * 8];
#pragma unroll
      for (int mt = 0; mt < 4; ++mt)
#pragma unroll
        for (int nt = 0; nt < 4; ++nt)
          acc[mt][nt] = __builtin_amdgcn_mfma_f32_16x16x32_bf16(a[mt], b[nt], acc[mt][nt], 0, 0, 0);
    }
    __syncthreads();
  }
  const bool odd = (ln & 1);
#pragma unroll
  for (int mt = 0; mt < 4; ++mt) {
    int rowb = bm + wm + mt * 16 + quad * 4;
#pragma unroll
    for (int nt = 0; nt < 4; ++nt) {
      int col = bn + wn + nt * 16 + ln;
      int h = col >> 7, d = col & 127;
#pragma unroll
      for (int r = 0; r < 4; ++r) {
        float v = acc[mt][nt][r];
        float other = __shfl_xor(v, 1);
        int row = rowb + r;
        int b = row >> 11, s = row & 2047;
        float y = v;
        if (d >= NOPED) {
          int i = (d - NOPED) >> 1;
          float theta = exp2f(-(float)i * (13.287712379549449f / 32.f));
          float ang = (float)s * theta;
          float sn, c;
          sincosf(ang, &sn, &c);
          y = v * c + (odd ? other * sn : -other * sn);
        }
        Qry[((size_t)(b * NH + h) * SEQ + s) * QKD + d] = f2bf(y);
      }
    }
  }
}

// ---------------- prep K: kvb nope + RoPE(cqkv rope cols) -> (B,H,S,128) -----
__global__ void prep_key(const unsigned short* __restrict__ kvb,
                         const unsigned short* __restrict__ cqkv,
                         unsigned short* __restrict__ Key) {
  __shared__ unsigned short krot[ROPED];
  int bs = blockIdx.x;
  int b = bs >> 11, s = bs & 2047;
  int tid = threadIdx.x;
  if (tid < 32) {
    int i = tid;
    float x0 = bf2f(cqkv[(size_t)bs * NCOMB + QRANK + KVRANK + 2 * i]);
    float x1 = bf2f(cqkv[(size_t)bs * NCOMB + QRANK + KVRANK + 2 * i + 1]);
    float theta = exp2f(-(float)i * (13.287712379549449f / 32.f));
    float ang = (float)s * theta;
    float sn, c;
    sincosf(ang, &sn, &c);
    krot[2 * i] = f2bf(x0 * c - x1 * sn);
    krot[2 * i + 1] = f2bf(x1 * c + x0 * sn);
  }
  __syncthreads();
  for (int idx = tid; idx < NH * QKD; idx += 256) {
    int h = idx >> 7, d = idx & 127;
    unsigned short v;
    if (d < NOPED)
      v = kvb[(size_t)bs * (NH * 192) + h * 192 + d];
    else
      v = krot[d - NOPED];
    Key[((size_t)(b * NH + h) * SEQ + s) * QKD + d] = v;
  }
}

// ---------------- transpose V: kvb[...,64:192] -> VT (B,H,128,S) ----------------
__global__ void transpose_v(const unsigned short* __restrict__ kvb, unsigned short* __restrict__ VT) {
  __shared__ unsigned short tile[64][132];
  int blk = blockIdx.x;
  int bh = blk >> 5, st = blk & 31;
  int b = bh >> 4, h = bh & 15;
  int s0 = st * 64;
  int tid = threadIdx.x;
  for (int idx = tid; idx < 64 * 128; idx += 256) {
    int sl = idx >> 7, d = idx & 127;
    tile[sl][d] = kvb[((size_t)(b * SEQ + s0 + sl)) * (NH * 192) + h * 192 + NOPED + d];
  }
  __syncthreads();
  for (int idx = tid; idx < 64 * 128; idx += 256) {
    int d = idx >> 6, sl = idx & 63;
    VT[((size_t)bh * VD + d) * SEQ + s0 + sl] = tile[sl][d];
  }
}

// ---------------- flash attention (R2 known-good): 128 q/block, 32q x 64k/wave
// Q,K: (BH, S, 128); VT: (BH, 128, S); O: (B, S, H*128) bf16.
// LDS 64KB (2 blocks/CU, grid-limited anyway). Q staged via global_load_lds,
// hoisted to regs, QP reused as P buffer. launch_bounds(256,2): no VGPR spill.
__global__ __launch_bounds__(256, 2) void flash_attn(
    const unsigned short* __restrict__ Q,
    const unsigned short* __restrict__ Kt,
    const unsigned short* __restrict__ VT,
    unsigned short* __restrict__ O)
{
  __shared__ __align__(16) unsigned short QP[128 * 128];  // Q staging, then P
  __shared__ __align__(16) unsigned short Ks[64 * 128];
  __shared__ __align__(16) unsigned short Vs[128 * 64];

  const int tid = threadIdx.x;
  const int wave = tid >> 6;
  const int lane = tid & 63;
  const int ln = lane & 15;
  const int quad = lane >> 4;
  const int bh = blockIdx.x;
  const int q0 = blockIdx.y * 128;

  // ---- stage Q (128x128), 16-chunk swizzle: slot(R,c) holds global chunk c^(R&15)
  {
    int rel = lane >> 4, cch = lane & 15;
#pragma unroll
    for (int it = 0; it < 8; ++it) {
      int rb = wave * 32 + it * 4;
      int rr = rb + rel;
      int c = cch ^ (rr & 15);
      gld_lds16(Q + ((size_t)bh * SEQ + q0 + rr) * QKD + c * 8, &QP[rb * 128]);
    }
  }
  __syncthreads();

  // ---- hoist Q a-frags
  s16x8 qa[2][4];
#pragma unroll
  for (int mt = 0; mt < 2; ++mt) {
    int row = wave * 32 + mt * 16 + ln;
#pragma unroll
    for (int kx = 0; kx < 4; ++kx)
      qa[mt][kx] = *(const s16x8*)&QP[row * 128 + ((kx * 4 + quad) ^ ln) * 8];
  }

  unsigned short* Pw = &QP[wave * 2048];  // 32 rows x 64 cols, row-pair swizzled

  f32x4 o[2][8] = {};
  float m_i[2][4], l_i[2][4];
#pragma unroll
  for (int mt = 0; mt < 2; ++mt)
#pragma unroll
    for (int r = 0; r < 4; ++r) { m_i[mt][r] = -1e30f; l_i[mt][r] = 0.f; }

  const bool even = ((ln & 1) == 0);

  for (int kt = 0; kt < SEQ / 64; ++kt) {
    {
      int rel = lane >> 4, cch = lane & 15;
#pragma unroll
      for (int it = 0; it < 4; ++it) {
        int rb = wave * 16 + it * 4;
        int rr = rb + rel;
        int c = cch ^ (rr & 15);
        gld_lds16(Kt + ((size_t)bh * SEQ + kt * 64 + rr) * QKD + c * 8, &Ks[rb * 128]);
      }
      int rel8 = lane >> 3;
      int c8 = (lane & 7) ^ rel8;
#pragma unroll
      for (int it = 0; it < 4; ++it) {
        int rb = wave * 32 + it * 8;
        gld_lds16(VT + ((size_t)bh * VD + rb + rel8) * SEQ + kt * 64 + c8 * 8, &Vs[rb * 64]);
      }
    }
    __syncthreads();

    // ---- S = Q K^T (32q x 64k per wave)
    f32x4 sc[2][4] = {};
#pragma unroll
    for (int kx = 0; kx < 4; ++kx) {
      s16x8 bk[4];
#pragma unroll
      for (int t = 0; t < 4; ++t)
        bk[t] = *(const s16x8*)&Ks[(t * 16 + ln) * 128 + ((kx * 4 + quad) ^ ln) * 8];
#pragma unroll
      for (int mt = 0; mt < 2; ++mt)
#pragma unroll
        for (int t = 0; t < 4; ++t)
          sc[mt][t] = __builtin_amdgcn_mfma_f32_16x16x32_bf16(qa[mt][kx], bk[t], sc[mt][t], 0, 0, 0);
    }

    // ---- online softmax
    float al[2][4];
#pragma unroll
    for (int mt = 0; mt < 2; ++mt) {
      float mx[4], rs[4];
#pragma unroll
      for (int r = 0; r < 4; ++r)
        mx[r] = fmaxf(fmaxf(sc[mt][0][r], sc[mt][1][r]), fmaxf(sc[mt][2][r], sc[mt][3][r]));
#pragma unroll
      for (int msk = 1; msk < 16; msk <<= 1)
#pragma unroll
        for (int r = 0; r < 4; ++r)
          mx[r] = fmaxf(mx[r], __shfl_xor(mx[r], msk));
#pragma unroll
      for (int r = 0; r < 4; ++r) {
        float mn = fmaxf(m_i[mt][r], mx[r]);
        al[mt][r] = __expf(m_i[mt][r] - mn);
        m_i[mt][r] = mn;
        rs[r] = 0.f;
      }
#pragma unroll
      for (int t = 0; t < 4; ++t)
#pragma unroll
        for (int r = 0; r < 4; ++r) {
          float e = __expf(sc[mt][t][r] - m_i[mt][r]);
          sc[mt][t][r] = e;
          rs[r] += e;
        }
#pragma unroll
      for (int msk = 1; msk < 16; msk <<= 1)
#pragma unroll
        for (int r = 0; r < 4; ++r)
          rs[r] += __shfl_xor(rs[r], msk);
#pragma unroll
      for (int r = 0; r < 4; ++r)
        l_i[mt][r] = l_i[mt][r] * al[mt][r] + rs[r];
#pragma unroll
      for (int dt = 0; dt < 8; ++dt)
#pragma unroll
        for (int r = 0; r < 4; ++r)
          o[mt][dt][r] *= al[mt][r];
    }

    // ---- P -> LDS (pack pairs via shfl, dword writes by even lanes)
#pragma unroll
    for (int mt = 0; mt < 2; ++mt)
#pragma unroll
      for (int t = 0; t < 4; ++t) {
        unsigned int pu[4], nu[4];
#pragma unroll
        for (int r = 0; r < 4; ++r) {
          pu[r] = __float_as_uint(sc[mt][t][r]);
          nu[r] = __float_as_uint(__shfl_xor(sc[mt][t][r], 1));
        }
        if (even) {
          int cb = t * 2 + (ln >> 3);
          int rbase = mt * 16 + quad * 4;
#pragma unroll
          for (int rp = 0; rp < 2; ++rp) {
            int swc = cb ^ (quad * 2 + rp);
            unsigned short* a = &Pw[(rbase + 2 * rp) * 64 + swc * 8 + (ln & 7)];
            *(unsigned int*)a        = (pu[2 * rp] >> 16)     | (nu[2 * rp] & 0xffff0000u);
            *(unsigned int*)(a + 64) = (pu[2 * rp + 1] >> 16) | (nu[2 * rp + 1] & 0xffff0000u);
          }
        }
      }
    asm volatile("s_waitcnt lgkmcnt(0)" ::: "memory");

    // ---- O += P @ V
#pragma unroll
    for (int kc = 0; kc < 2; ++kc) {
      s16x8 ap[2];
#pragma unroll
      for (int mt = 0; mt < 2; ++mt)
        ap[mt] = *(const s16x8*)&Pw[(mt * 16 + ln) * 64 + ((kc * 4 + quad) ^ (ln >> 1)) * 8];
#pragma unroll
      for (int dt = 0; dt < 8; ++dt) {
        s16x8 bv = *(const s16x8*)&Vs[(dt * 16 + ln) * 64 + ((kc * 4 + quad) ^ (ln & 7)) * 8];
#pragma unroll
        for (int mt = 0; mt < 2; ++mt)
          o[mt][dt] = __builtin_amdgcn_mfma_f32_16x16x32_bf16(ap[mt], bv, o[mt][dt], 0, 0, 0);
      }
    }
    __syncthreads();
  }

  const int b = bh >> 4, h = bh & 15;
#pragma unroll
  for (int mt = 0; mt < 2; ++mt)
#pragma unroll
    for (int r = 0; r < 4; ++r) {
      float inv = 1.f / l_i[mt][r];
      int s = q0 + wave * 32 + mt * 16 + quad * 4 + r;
      size_t rowbase = ((size_t)b * SEQ + s) * (NH * VD) + h * VD;
#pragma unroll
      for (int dt = 0; dt < 8; ++dt)
        O[rowbase + dt * 16 + ln] = f2bf(o[mt][dt][r] * inv);
    }
}

extern "C" void kernel_launch(void* const* d_in, const int* in_sizes, int n_in,
                              void* d_out, int out_size, void* d_ws, size_t ws_size,
                              hipStream_t stream) {
  const float* x_f    = (const float*)d_in[0];
  const float* qaw_f  = (const float*)d_in[1];
  const float* qbw_f  = (const float*)d_in[2];
  const float* kvaw_f = (const float*)d_in[3];
  const float* kvbw_f = (const float*)d_in[4];
  const float* ow_f   = (const float*)d_in[5];

  char* ws = (char*)d_ws;
  size_t off = 0;
  auto alloc = [&](size_t n) {
    unsigned short* p = (unsigned short*)(ws + off);
    off = (off + n * 2 + 255) & ~(size_t)255;
    return p;
  };
  unsigned short* Xb    = alloc((size_t)BS * EMB);
  unsigned short* Wcomb = alloc((size_t)NCOMB * EMB);
  unsigned short* Wqb   = alloc((size_t)(NH * QKD) * QRANK);
  unsigned short* Wkvb  = alloc((size_t)(NH * 192) * KVRANK);
  unsigned short* Wo    = alloc((size_t)EMB * (NH * VD));
  unsigned short* CQKV  = alloc((size_t)BS * NCOMB);
  unsigned short* KVB   = alloc((size_t)BS * (NH * 192));
  unsigned short* Qry   = alloc((size_t)BHD * SEQ * QKD);
  unsigned short* Key   = alloc((size_t)BHD * SEQ * QKD);
  unsigned short* Vt    = alloc((size_t)BHD * VD * SEQ);
  unsigned short* AO    = alloc((size_t)BS * (NH * VD));

  cast_all<<<dim3(8192), 256, 0, stream>>>(x_f, qaw_f, kvaw_f, qbw_f, kvbw_f, ow_f,
                                           Xb, Wcomb, Wqb, Wkvb, Wo);

  // [cq | ckv] = x @ [q_a_w; kv_a_w]^T  (4096 x 2112, K=2048)
  gemm_bt<0><<<dim3((NCOMB + 127) / 128, BS / 128), 256, 0, stream>>>(
      Xb, EMB, Wcomb, EMB, CQKV, BS, NCOMB, EMB);
  // q = cq @ q_b_w^T with fused RoPE + permuted store (4096 x 2048, K=1536)
  gemm_q_rope<<<dim3((NH * QKD) / 128, BS / 128), 256, 0, stream>>>(
      CQKV, NCOMB, Wqb, QRANK, Qry, QRANK);
  // kvb = ckv @ kv_b_w^T (4096 x 3072, K=512)
  gemm_bt<0><<<dim3((NH * 192) / 128, BS / 128), 256, 0, stream>>>(
      CQKV + QRANK, NCOMB, Wkvb, KVRANK, KVB, BS, NH * 192, KVRANK);

  prep_key<<<dim3(BS), 256, 0, stream>>>(KVB, CQKV, Key);
  transpose_v<<<dim3(BHD * (SEQ / 64)), 256, 0, stream>>>(KVB, Vt);

  flash_attn<<<dim3(BHD, SEQ / 128), 256, 0, stream>>>(Qry, Key, Vt, AO);

  // out = AO @ o_w^T (fp32 out)
  gemm_bt<1><<<dim3(EMB / 128, BS / 128), 256, 0, stream>>>(
      AO, NH * VD, Wo, NH * VD, d_out, BS, EMB, NH * VD);
}

// Round 5
// 432.740 us; speedup vs baseline: 1.3698x; 1.0016x over previous
//
#include <hip/hip_runtime.h>
#include <stdint.h>

#define EMB 2048
#define NH 16
#define QRANK 1536
#define KVRANK 512
#define ROPED 64
#define NOPED 64
#define VD 128
#define QKD 128
#define SEQ 2048
#define BATCH 2
#define BS 4096            // BATCH*SEQ
#define BHD 32             // BATCH*NH
#define NCOMB 2112         // QRANK + KVRANK + ROPED

typedef __attribute__((ext_vector_type(4))) float f32x4;
typedef __attribute__((ext_vector_type(8))) short s16x8;

__device__ __forceinline__ float bf2f(unsigned short u) {
  return __uint_as_float(((unsigned int)u) << 16);
}
__device__ __forceinline__ unsigned short f2bf(float f) {
  unsigned int u = __float_as_uint(f);
  u += 0x7fff + ((u >> 16) & 1);
  return (unsigned short)(u >> 16);
}

__device__ __forceinline__ void gld_lds16(const unsigned short* g, unsigned short* l) {
  __builtin_amdgcn_global_load_lds((const __attribute__((address_space(1))) void*)g,
                                   (__attribute__((address_space(3))) void*)l,
                                   16, 0, 0);
}

// ---------------- fused cast f32 -> bf16, all 6 tensors, one launch ----------
#define N4_X   (BS * EMB / 4)
#define N4_QA  (QRANK * EMB / 4)
#define N4_KVA ((KVRANK + ROPED) * EMB / 4)
#define N4_QB  (NH * QKD * QRANK / 4)
#define N4_KVB (NH * 192 * KVRANK / 4)
#define N4_O   (EMB * NH * VD / 4)
#define N4_TOT (N4_X + N4_QA + N4_KVA + N4_QB + N4_KVB + N4_O)

__global__ void cast_all(const float* __restrict__ x, const float* __restrict__ qa,
                         const float* __restrict__ kva, const float* __restrict__ qb,
                         const float* __restrict__ kvb, const float* __restrict__ ow,
                         unsigned short* __restrict__ Xb, unsigned short* __restrict__ Wcomb,
                         unsigned short* __restrict__ Wqb, unsigned short* __restrict__ Wkvb,
                         unsigned short* __restrict__ Wo) {
  int i = blockIdx.x * blockDim.x + threadIdx.x;
  int stride = gridDim.x * blockDim.x;
  for (; i < N4_TOT; i += stride) {
    const float4* src;
    ushort4* dst;
    int j = i;
    if (j < N4_X) { src = (const float4*)x; dst = (ushort4*)Xb; }
    else if ((j -= N4_X) < N4_QA) { src = (const float4*)qa; dst = (ushort4*)Wcomb; }
    else if ((j -= N4_QA) < N4_KVA) { src = (const float4*)kva; dst = (ushort4*)(Wcomb + (size_t)QRANK * EMB); }
    else if ((j -= N4_KVA) < N4_QB) { src = (const float4*)qb; dst = (ushort4*)Wqb; }
    else if ((j -= N4_QB) < N4_KVB) { src = (const float4*)kvb; dst = (ushort4*)Wkvb; }
    else { j -= N4_KVB; src = (const float4*)ow; dst = (ushort4*)Wo; }
    float4 v = src[j];
    ushort4 o;
    o.x = f2bf(v.x); o.y = f2bf(v.y); o.z = f2bf(v.z); o.w = f2bf(v.w);
    dst[j] = o;
  }
}

// ---------------- GEMM: C[M,N] = A[M,K(lda)] * W[N,K(ldw)]^T ----------------
// 128x128 tile, BK=64, 4 waves 2x2, each wave 64x64. 16B-chunk XOR swizzle.
template <int OUT_F32>
__global__ __launch_bounds__(256, 2) void gemm_bt(
    const unsigned short* __restrict__ A, int lda,
    const unsigned short* __restrict__ W, int ldw,
    void* __restrict__ C, int M, int N, int K)
{
  __shared__ __align__(16) unsigned short As[128 * 64];
  __shared__ __align__(16) unsigned short Ws[128 * 64];
  const int tid = threadIdx.x;
  const int wave = tid >> 6;
  const int lane = tid & 63;
  const int ln = lane & 15;
  const int quad = lane >> 4;
  const int bm = blockIdx.y * 128;
  const int bn = blockIdx.x * 128;
  const int wm = (wave >> 1) * 64;
  const int wn = (wave & 1) * 64;

  f32x4 acc[4][4] = {};

  const int rel8 = lane >> 3;
  const int csw = ((lane & 7) ^ rel8) * 8;

  for (int k0 = 0; k0 < K; k0 += 64) {
#pragma unroll
    for (int it = 0; it < 4; ++it) {
      int rb = wave * 32 + it * 8;
      gld_lds16(A + (size_t)(bm + rb + rel8) * lda + k0 + csw, &As[rb * 64]);
    }
#pragma unroll
    for (int it = 0; it < 4; ++it) {
      int rb = wave * 32 + it * 8;
      int wr = bn + rb + rel8;
      if (wr >= N) wr = N - 1;
      gld_lds16(W + (size_t)wr * ldw + k0 + csw, &Ws[rb * 64]);
    }
    __syncthreads();
#pragma unroll
    for (int kk = 0; kk < 64; kk += 32) {
      s16x8 a[4], b[4];
#pragma unroll
      for (int mt = 0; mt < 4; ++mt)
        a[mt] = *(const s16x8*)&As[(wm + mt * 16 + ln) * 64 + ((kk / 8 + quad) ^ (ln & 7)) * 8];
#pragma unroll
      for (int nt = 0; nt < 4; ++nt)
        b[nt] = *(const s16x8*)&Ws[(wn + nt * 16 + ln) * 64 + ((kk / 8 + quad) ^ (ln & 7)) * 8];
#pragma unroll
      for (int mt = 0; mt < 4; ++mt)
#pragma unroll
        for (int nt = 0; nt < 4; ++nt)
          acc[mt][nt] = __builtin_amdgcn_mfma_f32_16x16x32_bf16(a[mt], b[nt], acc[mt][nt], 0, 0, 0);
    }
    __syncthreads();
  }
#pragma unroll
  for (int mt = 0; mt < 4; ++mt) {
    int row = bm + wm + mt * 16 + quad * 4;
#pragma unroll
    for (int nt = 0; nt < 4; ++nt) {
      int col = bn + wn + nt * 16 + ln;
      if (col < N) {
#pragma unroll
        for (int r = 0; r < 4; ++r) {
          float v = acc[mt][nt][r];
          if (OUT_F32)
            ((float*)C)[(size_t)(row + r) * N + col] = v;
          else
            ((unsigned short*)C)[(size_t)(row + r) * N + col] = f2bf(v);
        }
      }
    }
  }
}

// ---------------- q GEMM with fused RoPE + (B,H,S,128) permuted store --------
__global__ __launch_bounds__(256, 2) void gemm_q_rope(
    const unsigned short* __restrict__ A, int lda,
    const unsigned short* __restrict__ W, int ldw,
    unsigned short* __restrict__ Qry, int K)
{
  __shared__ __align__(16) unsigned short As[128 * 64];
  __shared__ __align__(16) unsigned short Ws[128 * 64];
  const int tid = threadIdx.x;
  const int wave = tid >> 6;
  const int lane = tid & 63;
  const int ln = lane & 15;
  const int quad = lane >> 4;
  const int bm = blockIdx.y * 128;
  const int bn = blockIdx.x * 128;
  const int wm = (wave >> 1) * 64;
  const int wn = (wave & 1) * 64;

  f32x4 acc[4][4] = {};
  const int rel8 = lane >> 3;
  const int csw = ((lane & 7) ^ rel8) * 8;

  for (int k0 = 0; k0 < K; k0 += 64) {
#pragma unroll
    for (int it = 0; it < 4; ++it) {
      int rb = wave * 32 + it * 8;
      gld_lds16(A + (size_t)(bm + rb + rel8) * lda + k0 + csw, &As[rb * 64]);
    }
#pragma unroll
    for (int it = 0; it < 4; ++it) {
      int rb = wave * 32 + it * 8;
      gld_lds16(W + (size_t)(bn + rb + rel8) * ldw + k0 + csw, &Ws[rb * 64]);
    }
    __syncthreads();
#pragma unroll
    for (int kk = 0; kk < 64; kk += 32) {
      s16x8 a[4], b[4];
#pragma unroll
      for (int mt = 0; mt < 4; ++mt)
        a[mt] = *(const s16x8*)&As[(wm + mt * 16 + ln) * 64 + ((kk / 8 + quad) ^ (ln & 7)) * 8];
#pragma unroll
      for (int nt = 0; nt < 4; ++nt)
        b[nt] = *(const s16x8*)&Ws[(wn + nt * 16 + ln) * 64 + ((kk / 8 + quad) ^ (ln & 7)) * 8];
#pragma unroll
      for (int mt = 0; mt < 4; ++mt)
#pragma unroll
        for (int nt = 0; nt < 4; ++nt)
          acc[mt][nt] = __builtin_amdgcn_mfma_f32_16x16x32_bf16(a[mt], b[nt], acc[mt][nt], 0, 0, 0);
    }
    __syncthreads();
  }
  const bool odd = (ln & 1);
#pragma unroll
  for (int mt = 0; mt < 4; ++mt) {
    int rowb = bm + wm + mt * 16 + quad * 4;
#pragma unroll
    for (int nt = 0; nt < 4; ++nt) {
      int col = bn + wn + nt * 16 + ln;
      int h = col >> 7, d = col & 127;
#pragma unroll
      for (int r = 0; r < 4; ++r) {
        float v = acc[mt][nt][r];
        float other = __shfl_xor(v, 1);
        int row = rowb + r;
        int b = row >> 11, s = row & 2047;
        float y = v;
        if (d >= NOPED) {
          int i = (d - NOPED) >> 1;
          float theta = exp2f(-(float)i * (13.287712379549449f / 32.f));
          float ang = (float)s * theta;
          float sn, c;
          sincosf(ang, &sn, &c);
          y = v * c + (odd ? other * sn : -other * sn);
        }
        Qry[((size_t)(b * NH + h) * SEQ + s) * QKD + d] = f2bf(y);
      }
    }
  }
}

// ---------------- prep K: kvb nope + RoPE(cqkv rope cols) -> (B,H,S,128) -----
__global__ void prep_key(const unsigned short* __restrict__ kvb,
                         const unsigned short* __restrict__ cqkv,
                         unsigned short* __restrict__ Key) {
  __shared__ unsigned short krot[ROPED];
  int bs = blockIdx.x;
  int b = bs >> 11, s = bs & 2047;
  int tid = threadIdx.x;
  if (tid < 32) {
    int i = tid;
    float x0 = bf2f(cqkv[(size_t)bs * NCOMB + QRANK + KVRANK + 2 * i]);
    float x1 = bf2f(cqkv[(size_t)bs * NCOMB + QRANK + KVRANK + 2 * i + 1]);
    float theta = exp2f(-(float)i * (13.287712379549449f / 32.f));
    float ang = (float)s * theta;
    float sn, c;
    sincosf(ang, &sn, &c);
    krot[2 * i] = f2bf(x0 * c - x1 * sn);
    krot[2 * i + 1] = f2bf(x1 * c + x0 * sn);
  }
  __syncthreads();
  for (int idx = tid; idx < NH * QKD; idx += 256) {
    int h = idx >> 7, d = idx & 127;
    unsigned short v;
    if (d < NOPED)
      v = kvb[(size_t)bs * (NH * 192) + h * 192 + d];
    else
      v = krot[d - NOPED];
    Key[((size_t)(b * NH + h) * SEQ + s) * QKD + d] = v;
  }
}

// ---------------- transpose V: kvb[...,64:192] -> VT (B,H,128,S) ----------------
__global__ void transpose_v(const unsigned short* __restrict__ kvb, unsigned short* __restrict__ VT) {
  __shared__ unsigned short tile[64][132];
  int blk = blockIdx.x;
  int bh = blk >> 5, st = blk & 31;
  int b = bh >> 4, h = bh & 15;
  int s0 = st * 64;
  int tid = threadIdx.x;
  for (int idx = tid; idx < 64 * 128; idx += 256) {
    int sl = idx >> 7, d = idx & 127;
    tile[sl][d] = kvb[((size_t)(b * SEQ + s0 + sl)) * (NH * 192) + h * 192 + NOPED + d];
  }
  __syncthreads();
  for (int idx = tid; idx < 64 * 128; idx += 256) {
    int d = idx >> 6, sl = idx & 63;
    VT[((size_t)bh * VD + d) * SEQ + s0 + sl] = tile[sl][d];
  }
}

// ---------------- flash attention v4: Q direct to regs, 48KB LDS -------------
// Q,K: (BH, S, 128); VT: (BH, 128, S); O: (B, S, H*128) bf16.
// launch_bounds(256,2) — 2nd arg stays 2 so the allocator keeps ~124 VGPR (R3's
// (256,3) forced VGPR->84 and spilled ~26MB to scratch). With LDS=48KB the HW
// schedules 3 blocks/CU anyway (160/48=3.3, VGPR allows 4 waves/SIMD).
__global__ __launch_bounds__(256, 2) void flash_attn(
    const unsigned short* __restrict__ Q,
    const unsigned short* __restrict__ Kt,
    const unsigned short* __restrict__ VT,
    unsigned short* __restrict__ O)
{
  __shared__ __align__(16) unsigned short Ks[64 * 128];
  __shared__ __align__(16) unsigned short Vs[128 * 64];
  __shared__ __align__(16) unsigned short Ps[4 * 2048];

  const int tid = threadIdx.x;
  const int wave = tid >> 6;
  const int lane = tid & 63;
  const int ln = lane & 15;
  const int quad = lane >> 4;
  const int bh = blockIdx.x;
  const int q0 = blockIdx.y * 128;

  // ---- Q a-frags straight from global (rows wave*32+mt*16+ln, k = kx*32+quad*8)
  s16x8 qa[2][4];
#pragma unroll
  for (int mt = 0; mt < 2; ++mt) {
    const unsigned short* qrow = Q + ((size_t)bh * SEQ + q0 + wave * 32 + mt * 16 + ln) * QKD;
#pragma unroll
    for (int kx = 0; kx < 4; ++kx)
      qa[mt][kx] = *(const s16x8*)(qrow + kx * 32 + quad * 8);
  }

  unsigned short* Pw = &Ps[wave * 2048];  // 32 rows x 64 cols, row-pair swizzled

  f32x4 o[2][8] = {};
  float m_i[2][4], l_i[2][4];
#pragma unroll
  for (int mt = 0; mt < 2; ++mt)
#pragma unroll
    for (int r = 0; r < 4; ++r) { m_i[mt][r] = -1e30f; l_i[mt][r] = 0.f; }

  const bool even = ((ln & 1) == 0);

  for (int kt = 0; kt < SEQ / 64; ++kt) {
    // stage K (64x128, 16-chunk swizzle) and V^T (128x64, 8-chunk swizzle)
    {
      int rel = lane >> 4, cch = lane & 15;
#pragma unroll
      for (int it = 0; it < 4; ++it) {
        int rb = wave * 16 + it * 4;
        int rr = rb + rel;
        int c = cch ^ (rr & 15);
        gld_lds16(Kt + ((size_t)bh * SEQ + kt * 64 + rr) * QKD + c * 8, &Ks[rb * 128]);
      }
      int rel8 = lane >> 3;
      int c8 = (lane & 7) ^ rel8;
#pragma unroll
      for (int it = 0; it < 4; ++it) {
        int rb = wave * 32 + it * 8;
        gld_lds16(VT + ((size_t)bh * VD + rb + rel8) * SEQ + kt * 64 + c8 * 8, &Vs[rb * 64]);
      }
    }
    __syncthreads();

    // ---- S = Q K^T (32q x 64k per wave)
    f32x4 sc[2][4] = {};
#pragma unroll
    for (int kx = 0; kx < 4; ++kx) {
      s16x8 bk[4];
#pragma unroll
      for (int t = 0; t < 4; ++t)
        bk[t] = *(const s16x8*)&Ks[(t * 16 + ln) * 128 + ((kx * 4 + quad) ^ ln) * 8];
#pragma unroll
      for (int mt = 0; mt < 2; ++mt)
#pragma unroll
        for (int t = 0; t < 4; ++t)
          sc[mt][t] = __builtin_amdgcn_mfma_f32_16x16x32_bf16(qa[mt][kx], bk[t], sc[mt][t], 0, 0, 0);
    }

    // ---- online softmax per (mt, r); row = mt*16 + quad*4 + r
    float al[2][4];
#pragma unroll
    for (int mt = 0; mt < 2; ++mt) {
      float mx[4], rs[4];
#pragma unroll
      for (int r = 0; r < 4; ++r)
        mx[r] = fmaxf(fmaxf(sc[mt][0][r], sc[mt][1][r]), fmaxf(sc[mt][2][r], sc[mt][3][r]));
#pragma unroll
      for (int msk = 1; msk < 16; msk <<= 1)
#pragma unroll
        for (int r = 0; r < 4; ++r)
          mx[r] = fmaxf(mx[r], __shfl_xor(mx[r], msk));
#pragma unroll
      for (int r = 0; r < 4; ++r) {
        float mn = fmaxf(m_i[mt][r], mx[r]);
        al[mt][r] = __expf(m_i[mt][r] - mn);
        m_i[mt][r] = mn;
        rs[r] = 0.f;
      }
#pragma unroll
      for (int t = 0; t < 4; ++t)
#pragma unroll
        for (int r = 0; r < 4; ++r) {
          float e = __expf(sc[mt][t][r] - m_i[mt][r]);
          sc[mt][t][r] = e;
          rs[r] += e;
        }
#pragma unroll
      for (int msk = 1; msk < 16; msk <<= 1)
#pragma unroll
        for (int r = 0; r < 4; ++r)
          rs[r] += __shfl_xor(rs[r], msk);
#pragma unroll
      for (int r = 0; r < 4; ++r)
        l_i[mt][r] = l_i[mt][r] * al[mt][r] + rs[r];
#pragma unroll
      for (int dt = 0; dt < 8; ++dt)
#pragma unroll
        for (int r = 0; r < 4; ++r)
          o[mt][dt][r] *= al[mt][r];
    }

    // ---- P -> LDS (pack pairs via shfl, dword writes by even lanes)
#pragma unroll
    for (int mt = 0; mt < 2; ++mt)
#pragma unroll
      for (int t = 0; t < 4; ++t) {
        unsigned int pu[4], nu[4];
#pragma unroll
        for (int r = 0; r < 4; ++r) {
          pu[r] = __float_as_uint(sc[mt][t][r]);
          nu[r] = __float_as_uint(__shfl_xor(sc[mt][t][r], 1));
        }
        if (even) {
          int cb = t * 2 + (ln >> 3);
          int rbase = mt * 16 + quad * 4;
#pragma unroll
          for (int rp = 0; rp < 2; ++rp) {
            int swc = cb ^ (quad * 2 + rp);
            unsigned short* a = &Pw[(rbase + 2 * rp) * 64 + swc * 8 + (ln & 7)];
            *(unsigned int*)a        = (pu[2 * rp] >> 16)     | (nu[2 * rp] & 0xffff0000u);
            *(unsigned int*)(a + 64) = (pu[2 * rp + 1] >> 16) | (nu[2 * rp + 1] & 0xffff0000u);
          }
        }
      }
    asm volatile("s_waitcnt lgkmcnt(0)" ::: "memory");

    // ---- O += P @ V
#pragma unroll
    for (int kc = 0; kc < 2; ++kc) {
      s16x8 ap[2];
#pragma unroll
      for (int mt = 0; mt < 2; ++mt)
        ap[mt] = *(const s16x8*)&Pw[(mt * 16 + ln) * 64 + ((kc * 4 + quad) ^ (ln >> 1)) * 8];
#pragma unroll
      for (int dt = 0; dt < 8; ++dt) {
        s16x8 bv = *(const s16x8*)&Vs[(dt * 16 + ln) * 64 + ((kc * 4 + quad) ^ (ln & 7)) * 8];
#pragma unroll
        for (int mt = 0; mt < 2; ++mt)
          o[mt][dt] = __builtin_amdgcn_mfma_f32_16x16x32_bf16(ap[mt], bv, o[mt][dt], 0, 0, 0);
      }
    }
    __syncthreads();
  }

  const int b = bh >> 4, h = bh & 15;
#pragma unroll
  for (int mt = 0; mt < 2; ++mt)
#pragma unroll
    for (int r = 0; r < 4; ++r) {
      float inv = 1.f / l_i[mt][r];
      int s = q0 + wave * 32 + mt * 16 + quad * 4 + r;
      size_t rowbase = ((size_t)b * SEQ + s) * (NH * VD) + h * VD;
#pragma unroll
      for (int dt = 0; dt < 8; ++dt)
        O[rowbase + dt * 16 + ln] = f2bf(o[mt][dt][r] * inv);
    }
}

extern "C" void kernel_launch(void* const* d_in, const int* in_sizes, int n_in,
                              void* d_out, int out_size, void* d_ws, size_t ws_size,
                              hipStream_t stream) {
  const float* x_f    = (const float*)d_in[0];
  const float* qaw_f  = (const float*)d_in[1];
  const float* qbw_f  = (const float*)d_in[2];
  const float* kvaw_f = (const float*)d_in[3];
  const float* kvbw_f = (const float*)d_in[4];
  const float* ow_f   = (const float*)d_in[5];

  char* ws = (char*)d_ws;
  size_t off = 0;
  auto alloc = [&](size_t n) {
    unsigned short* p = (unsigned short*)(ws + off);
    off = (off + n * 2 + 255) & ~(size_t)255;
    return p;
  };
  unsigned short* Xb    = alloc((size_t)BS * EMB);
  unsigned short* Wcomb = alloc((size_t)NCOMB * EMB);
  unsigned short* Wqb   = alloc((size_t)(NH * QKD) * QRANK);
  unsigned short* Wkvb  = alloc((size_t)(NH * 192) * KVRANK);
  unsigned short* Wo    = alloc((size_t)EMB * (NH * VD));
  unsigned short* CQKV  = alloc((size_t)BS * NCOMB);
  unsigned short* KVB   = alloc((size_t)BS * (NH * 192));
  unsigned short* Qry   = alloc((size_t)BHD * SEQ * QKD);
  unsigned short* Key   = alloc((size_t)BHD * SEQ * QKD);
  unsigned short* Vt    = alloc((size_t)BHD * VD * SEQ);
  unsigned short* AO    = alloc((size_t)BS * (NH * VD));

  cast_all<<<dim3(8192), 256, 0, stream>>>(x_f, qaw_f, kvaw_f, qbw_f, kvbw_f, ow_f,
                                           Xb, Wcomb, Wqb, Wkvb, Wo);

  // [cq | ckv] = x @ [q_a_w; kv_a_w]^T  (4096 x 2112, K=2048)
  gemm_bt<0><<<dim3((NCOMB + 127) / 128, BS / 128), 256, 0, stream>>>(
      Xb, EMB, Wcomb, EMB, CQKV, BS, NCOMB, EMB);
  // q = cq @ q_b_w^T with fused RoPE + permuted store (4096 x 2048, K=1536)
  gemm_q_rope<<<dim3((NH * QKD) / 128, BS / 128), 256, 0, stream>>>(
      CQKV, NCOMB, Wqb, QRANK, Qry, QRANK);
  // kvb = ckv @ kv_b_w^T (4096 x 3072, K=512)
  gemm_bt<0><<<dim3((NH * 192) / 128, BS / 128), 256, 0, stream>>>(
      CQKV + QRANK, NCOMB, Wkvb, KVRANK, KVB, BS, NH * 192, KVRANK);

  prep_key<<<dim3(BS), 256, 0, stream>>>(KVB, CQKV, Key);
  transpose_v<<<dim3(BHD * (SEQ / 64)), 256, 0, stream>>>(KVB, Vt);

  flash_attn<<<dim3(BHD, SEQ / 128), 256, 0, stream>>>(Qry, Key, Vt, AO);

  // out = AO @ o_w^T (fp32 out)
  gemm_bt<1><<<dim3(EMB / 128, BS / 128), 256, 0, stream>>>(
      AO, NH * VD, Wo, NH * VD, d_out, BS, EMB, NH * VD);
}

// Round 6
// 399.588 us; speedup vs baseline: 1.4834x; 1.0830x over previous
//
#include <hip/hip_runtime.h>
#include <stdint.h>

#define EMB 2048
#define NH 16
#define QRANK 1536
#define KVRANK 512
#define ROPED 64
#define NOPED 64
#define VD 128
#define QKD 128
#define SEQ 2048
#define BATCH 2
#define BS 4096            // BATCH*SEQ
#define BHD 32             // BATCH*NH
#define NCOMB 2112         // QRANK + KVRANK + ROPED

typedef __attribute__((ext_vector_type(4))) float f32x4;
typedef __attribute__((ext_vector_type(8))) short s16x8;
typedef __attribute__((ext_vector_type(4))) short s16x4;

__device__ __forceinline__ float bf2f(unsigned short u) {
  return __uint_as_float(((unsigned int)u) << 16);
}
__device__ __forceinline__ unsigned short f2bf(float f) {
  unsigned int u = __float_as_uint(f);
  u += 0x7fff + ((u >> 16) & 1);
  return (unsigned short)(u >> 16);
}

__device__ __forceinline__ f32x4 mfma16k16(s16x4 a, s16x4 b, f32x4 c) {
#if __has_builtin(__builtin_amdgcn_mfma_f32_16x16x16_bf16)
  return __builtin_amdgcn_mfma_f32_16x16x16_bf16(a, b, c, 0, 0, 0);
#else
  return __builtin_amdgcn_mfma_f32_16x16x16bf16_1k(a, b, c, 0, 0, 0);
#endif
}

__device__ __forceinline__ void gld_lds16(const unsigned short* g, unsigned short* l) {
  __builtin_amdgcn_global_load_lds((const __attribute__((address_space(1))) void*)g,
                                   (__attribute__((address_space(3))) void*)l,
                                   16, 0, 0);
}

// ---------------- fused cast f32 -> bf16, all 6 tensors, one launch ----------
#define N4_X   (BS * EMB / 4)
#define N4_QA  (QRANK * EMB / 4)
#define N4_KVA ((KVRANK + ROPED) * EMB / 4)
#define N4_QB  (NH * QKD * QRANK / 4)
#define N4_KVB (NH * 192 * KVRANK / 4)
#define N4_O   (EMB * NH * VD / 4)
#define N4_TOT (N4_X + N4_QA + N4_KVA + N4_QB + N4_KVB + N4_O)

__global__ void cast_all(const float* __restrict__ x, const float* __restrict__ qa,
                         const float* __restrict__ kva, const float* __restrict__ qb,
                         const float* __restrict__ kvb, const float* __restrict__ ow,
                         unsigned short* __restrict__ Xb, unsigned short* __restrict__ Wcomb,
                         unsigned short* __restrict__ Wqb, unsigned short* __restrict__ Wkvb,
                         unsigned short* __restrict__ Wo) {
  int i = blockIdx.x * blockDim.x + threadIdx.x;
  int stride = gridDim.x * blockDim.x;
  for (; i < N4_TOT; i += stride) {
    const float4* src;
    ushort4* dst;
    int j = i;
    if (j < N4_X) { src = (const float4*)x; dst = (ushort4*)Xb; }
    else if ((j -= N4_X) < N4_QA) { src = (const float4*)qa; dst = (ushort4*)Wcomb; }
    else if ((j -= N4_QA) < N4_KVA) { src = (const float4*)kva; dst = (ushort4*)(Wcomb + (size_t)QRANK * EMB); }
    else if ((j -= N4_KVA) < N4_QB) { src = (const float4*)qb; dst = (ushort4*)Wqb; }
    else if ((j -= N4_QB) < N4_KVB) { src = (const float4*)kvb; dst = (ushort4*)Wkvb; }
    else { j -= N4_KVB; src = (const float4*)ow; dst = (ushort4*)Wo; }
    float4 v = src[j];
    ushort4 o;
    o.x = f2bf(v.x); o.y = f2bf(v.y); o.z = f2bf(v.z); o.w = f2bf(v.w);
    dst[j] = o;
  }
}

// ---------------- GEMM: C[M,N] = A[M,K(lda)] * W[N,K(ldw)]^T ----------------
// 128x128 tile, BK=64, 4 waves 2x2, each wave 64x64. 16B-chunk XOR swizzle.
template <int OUT_F32>
__global__ __launch_bounds__(256, 2) void gemm_bt(
    const unsigned short* __restrict__ A, int lda,
    const unsigned short* __restrict__ W, int ldw,
    void* __restrict__ C, int M, int N, int K)
{
  __shared__ __align__(16) unsigned short As[128 * 64];
  __shared__ __align__(16) unsigned short Ws[128 * 64];
  const int tid = threadIdx.x;
  const int wave = tid >> 6;
  const int lane = tid & 63;
  const int ln = lane & 15;
  const int quad = lane >> 4;
  const int bm = blockIdx.y * 128;
  const int bn = blockIdx.x * 128;
  const int wm = (wave >> 1) * 64;
  const int wn = (wave & 1) * 64;

  f32x4 acc[4][4] = {};

  const int rel8 = lane >> 3;
  const int csw = ((lane & 7) ^ rel8) * 8;

  for (int k0 = 0; k0 < K; k0 += 64) {
#pragma unroll
    for (int it = 0; it < 4; ++it) {
      int rb = wave * 32 + it * 8;
      gld_lds16(A + (size_t)(bm + rb + rel8) * lda + k0 + csw, &As[rb * 64]);
    }
#pragma unroll
    for (int it = 0; it < 4; ++it) {
      int rb = wave * 32 + it * 8;
      int wr = bn + rb + rel8;
      if (wr >= N) wr = N - 1;
      gld_lds16(W + (size_t)wr * ldw + k0 + csw, &Ws[rb * 64]);
    }
    __syncthreads();
#pragma unroll
    for (int kk = 0; kk < 64; kk += 32) {
      s16x8 a[4], b[4];
#pragma unroll
      for (int mt = 0; mt < 4; ++mt)
        a[mt] = *(const s16x8*)&As[(wm + mt * 16 + ln) * 64 + ((kk / 8 + quad) ^ (ln & 7)) * 8];
#pragma unroll
      for (int nt = 0; nt < 4; ++nt)
        b[nt] = *(const s16x8*)&Ws[(wn + nt * 16 + ln) * 64 + ((kk / 8 + quad) ^ (ln & 7)) * 8];
#pragma unroll
      for (int mt = 0; mt < 4; ++mt)
#pragma unroll
        for (int nt = 0; nt < 4; ++nt)
          acc[mt][nt] = __builtin_amdgcn_mfma_f32_16x16x32_bf16(a[mt], b[nt], acc[mt][nt], 0, 0, 0);
    }
    __syncthreads();
  }
#pragma unroll
  for (int mt = 0; mt < 4; ++mt) {
    int row = bm + wm + mt * 16 + quad * 4;
#pragma unroll
    for (int nt = 0; nt < 4; ++nt) {
      int col = bn + wn + nt * 16 + ln;
      if (col < N) {
#pragma unroll
        for (int r = 0; r < 4; ++r) {
          float v = acc[mt][nt][r];
          if (OUT_F32)
            ((float*)C)[(size_t)(row + r) * N + col] = v;
          else
            ((unsigned short*)C)[(size_t)(row + r) * N + col] = f2bf(v);
        }
      }
    }
  }
}

// ---------------- q GEMM with fused RoPE + (B,H,S,128) permuted store --------
__global__ __launch_bounds__(256, 2) void gemm_q_rope(
    const unsigned short* __restrict__ A, int lda,
    const unsigned short* __restrict__ W, int ldw,
    unsigned short* __restrict__ Qry, int K)
{
  __shared__ __align__(16) unsigned short As[128 * 64];
  __shared__ __align__(16) unsigned short Ws[128 * 64];
  const int tid = threadIdx.x;
  const int wave = tid >> 6;
  const int lane = tid & 63;
  const int ln = lane & 15;
  const int quad = lane >> 4;
  const int bm = blockIdx.y * 128;
  const int bn = blockIdx.x * 128;
  const int wm = (wave >> 1) * 64;
  const int wn = (wave & 1) * 64;

  f32x4 acc[4][4] = {};
  const int rel8 = lane >> 3;
  const int csw = ((lane & 7) ^ rel8) * 8;

  for (int k0 = 0; k0 < K; k0 += 64) {
#pragma unroll
    for (int it = 0; it < 4; ++it) {
      int rb = wave * 32 + it * 8;
      gld_lds16(A + (size_t)(bm + rb + rel8) * lda + k0 + csw, &As[rb * 64]);
    }
#pragma unroll
    for (int it = 0; it < 4; ++it) {
      int rb = wave * 32 + it * 8;
      gld_lds16(W + (size_t)(bn + rb + rel8) * ldw + k0 + csw, &Ws[rb * 64]);
    }
    __syncthreads();
#pragma unroll
    for (int kk = 0; kk < 64; kk += 32) {
      s16x8 a[4], b[4];
#pragma unroll
      for (int mt = 0; mt < 4; ++mt)
        a[mt] = *(const s16x8*)&As[(wm + mt * 16 + ln) * 64 + ((kk / 8 + quad) ^ (ln & 7)) * 8];
#pragma unroll
      for (int nt = 0; nt < 4; ++nt)
        b[nt] = *(const s16x8*)&Ws[(wn + nt * 16 + ln) * 64 + ((kk / 8 + quad) ^ (ln & 7)) * 8];
#pragma unroll
      for (int mt = 0; mt < 4; ++mt)
#pragma unroll
        for (int nt = 0; nt < 4; ++nt)
          acc[mt][nt] = __builtin_amdgcn_mfma_f32_16x16x32_bf16(a[mt], b[nt], acc[mt][nt], 0, 0, 0);
    }
    __syncthreads();
  }
  const bool odd = (ln & 1);
#pragma unroll
  for (int mt = 0; mt < 4; ++mt) {
    int rowb = bm + wm + mt * 16 + quad * 4;
#pragma unroll
    for (int nt = 0; nt < 4; ++nt) {
      int col = bn + wn + nt * 16 + ln;
      int h = col >> 7, d = col & 127;
#pragma unroll
      for (int r = 0; r < 4; ++r) {
        float v = acc[mt][nt][r];
        float other = __shfl_xor(v, 1);
        int row = rowb + r;
        int b = row >> 11, s = row & 2047;
        float y = v;
        if (d >= NOPED) {
          int i = (d - NOPED) >> 1;
          float theta = exp2f(-(float)i * (13.287712379549449f / 32.f));
          float ang = (float)s * theta;
          float sn, c;
          sincosf(ang, &sn, &c);
          y = v * c + (odd ? other * sn : -other * sn);
        }
        Qry[((size_t)(b * NH + h) * SEQ + s) * QKD + d] = f2bf(y);
      }
    }
  }
}

// ---------------- prep K: kvb nope + RoPE(cqkv rope cols) -> (B,H,S,128) -----
__global__ void prep_key(const unsigned short* __restrict__ kvb,
                         const unsigned short* __restrict__ cqkv,
                         unsigned short* __restrict__ Key) {
  __shared__ unsigned short krot[ROPED];
  int bs = blockIdx.x;
  int b = bs >> 11, s = bs & 2047;
  int tid = threadIdx.x;
  if (tid < 32) {
    int i = tid;
    float x0 = bf2f(cqkv[(size_t)bs * NCOMB + QRANK + KVRANK + 2 * i]);
    float x1 = bf2f(cqkv[(size_t)bs * NCOMB + QRANK + KVRANK + 2 * i + 1]);
    float theta = exp2f(-(float)i * (13.287712379549449f / 32.f));
    float ang = (float)s * theta;
    float sn, c;
    sincosf(ang, &sn, &c);
    krot[2 * i] = f2bf(x0 * c - x1 * sn);
    krot[2 * i + 1] = f2bf(x1 * c + x0 * sn);
  }
  __syncthreads();
  for (int idx = tid; idx < NH * QKD; idx += 256) {
    int h = idx >> 7, d = idx & 127;
    unsigned short v;
    if (d < NOPED)
      v = kvb[(size_t)bs * (NH * 192) + h * 192 + d];
    else
      v = krot[d - NOPED];
    Key[((size_t)(b * NH + h) * SEQ + s) * QKD + d] = v;
  }
}

// ---------------- transpose V: kvb[...,64:192] -> VT (B,H,128,S) ----------------
__global__ void transpose_v(const unsigned short* __restrict__ kvb, unsigned short* __restrict__ VT) {
  __shared__ unsigned short tile[64][132];
  int blk = blockIdx.x;
  int bh = blk >> 5, st = blk & 31;
  int b = bh >> 4, h = bh & 15;
  int s0 = st * 64;
  int tid = threadIdx.x;
  for (int idx = tid; idx < 64 * 128; idx += 256) {
    int sl = idx >> 7, d = idx & 127;
    tile[sl][d] = kvb[((size_t)(b * SEQ + s0 + sl)) * (NH * 192) + h * 192 + NOPED + d];
  }
  __syncthreads();
  for (int idx = tid; idx < 64 * 128; idx += 256) {
    int d = idx >> 6, sl = idx & 63;
    VT[((size_t)bh * VD + d) * SEQ + s0 + sl] = tile[sl][d];
  }
}

// ---------------- flash attention v5: S^T trick, no P LDS round-trip ---------
// Computes S^T = K·Q^T so the score C-layout (row=key=quad*4+reg, col=q=ln)
// directly matches the B-operand k-mapping (k=quad*4+j) of mfma 16x16x16 —
// exp(S^T) converts in-register to the PV B-fragment. PV: O^T = V^T · P^T with
// V as A-operand (b64 granule reads from swizzled Vs). 32KB LDS. Softmax
// reductions collapse to shfl_xor(16/32); alpha is one scalar per lane.
__global__ __launch_bounds__(256, 2) void flash_attn(
    const unsigned short* __restrict__ Q,
    const unsigned short* __restrict__ Kt,
    const unsigned short* __restrict__ VT,
    unsigned short* __restrict__ O)
{
  __shared__ __align__(16) unsigned short Ks[64 * 128];
  __shared__ __align__(16) unsigned short Vs[128 * 64];

  const int tid = threadIdx.x;
  const int wave = tid >> 6;
  const int lane = tid & 63;
  const int ln = lane & 15;
  const int quad = lane >> 4;
  const int bh = blockIdx.x;
  const int q0 = blockIdx.y * 128;

  // ---- Q fragments straight from global; per-lane layout (n=ln, k=quad*8+j)
  // serves as the B-operand of the S^T = K·Q^T MFMA.
  s16x8 qa[2][4];
#pragma unroll
  for (int mt = 0; mt < 2; ++mt) {
    const unsigned short* qrow = Q + ((size_t)bh * SEQ + q0 + wave * 32 + mt * 16 + ln) * QKD;
#pragma unroll
    for (int kx = 0; kx < 4; ++kx)
      qa[mt][kx] = *(const s16x8*)(qrow + kx * 32 + quad * 8);
  }

  f32x4 o[2][8] = {};              // o[mt][dt]: d = dt*16+quad*4+r, q = mt*16+ln
  float m_i[2] = {-1e30f, -1e30f};
  float l_i[2] = {0.f, 0.f};

  for (int kt = 0; kt < SEQ / 64; ++kt) {
    // stage K (64x128, 16-chunk swizzle) and V^T (128x64, 8-chunk swizzle)
    {
      int rel = lane >> 4, cch = lane & 15;
#pragma unroll
      for (int it = 0; it < 4; ++it) {
        int rb = wave * 16 + it * 4;
        int rr = rb + rel;
        int c = cch ^ (rr & 15);
        gld_lds16(Kt + ((size_t)bh * SEQ + kt * 64 + rr) * QKD + c * 8, &Ks[rb * 128]);
      }
      int rel8 = lane >> 3;
      int c8 = (lane & 7) ^ rel8;
#pragma unroll
      for (int it = 0; it < 4; ++it) {
        int rb = wave * 32 + it * 8;
        gld_lds16(VT + ((size_t)bh * VD + rb + rel8) * SEQ + kt * 64 + c8 * 8, &Vs[rb * 64]);
      }
    }
    __syncthreads();

    // ---- S^T = K·Q^T: sc[mt][t] rows = keys t*16+quad*4+r, col = q = ln
    f32x4 sc[2][4] = {};
#pragma unroll
    for (int kx = 0; kx < 4; ++kx) {
      s16x8 ak[4];
#pragma unroll
      for (int t = 0; t < 4; ++t)
        ak[t] = *(const s16x8*)&Ks[(t * 16 + ln) * 128 + ((kx * 4 + quad) ^ ln) * 8];
#pragma unroll
      for (int mt = 0; mt < 2; ++mt)
#pragma unroll
        for (int t = 0; t < 4; ++t)
          sc[mt][t] = __builtin_amdgcn_mfma_f32_16x16x32_bf16(ak[t], qa[mt][kx], sc[mt][t], 0, 0, 0);
    }

    // ---- online softmax (per q = lane column); P^T stays in registers
    s16x4 pb[2][4];
#pragma unroll
    for (int mt = 0; mt < 2; ++mt) {
      float mx = sc[mt][0][0];
#pragma unroll
      for (int t = 0; t < 4; ++t)
#pragma unroll
        for (int r = 0; r < 4; ++r)
          mx = fmaxf(mx, sc[mt][t][r]);
      mx = fmaxf(mx, __shfl_xor(mx, 16));
      mx = fmaxf(mx, __shfl_xor(mx, 32));
      float mn = fmaxf(m_i[mt], mx);
      float al = __expf(m_i[mt] - mn);
      m_i[mt] = mn;
      float rs = 0.f;
#pragma unroll
      for (int t = 0; t < 4; ++t) {
        float e0 = __expf(sc[mt][t][0] - mn);
        float e1 = __expf(sc[mt][t][1] - mn);
        float e2 = __expf(sc[mt][t][2] - mn);
        float e3 = __expf(sc[mt][t][3] - mn);
        rs += (e0 + e1) + (e2 + e3);
        s16x4 p;
        p[0] = (short)f2bf(e0); p[1] = (short)f2bf(e1);
        p[2] = (short)f2bf(e2); p[3] = (short)f2bf(e3);
        pb[mt][t] = p;
      }
      rs += __shfl_xor(rs, 16);
      rs += __shfl_xor(rs, 32);
      l_i[mt] = l_i[mt] * al + rs;
#pragma unroll
      for (int dt = 0; dt < 8; ++dt)
#pragma unroll
        for (int r = 0; r < 4; ++r)
          o[mt][dt][r] *= al;
    }

    // ---- O^T += V^T · P^T (A = V granules from Vs, B = pb in registers)
#pragma unroll
    for (int kc = 0; kc < 4; ++kc) {
      int gsl = ((kc * 2 + (quad >> 1)) ^ (ln & 7)) * 8 + (quad & 1) * 4;
#pragma unroll
      for (int dt = 0; dt < 8; ++dt) {
        s16x4 av = *(const s16x4*)&Vs[(dt * 16 + ln) * 64 + gsl];
#pragma unroll
        for (int mt = 0; mt < 2; ++mt)
          o[mt][dt] = mfma16k16(av, pb[mt][kc], o[mt][dt]);
      }
    }
    __syncthreads();
  }

  const int b = bh >> 4, h = bh & 15;
#pragma unroll
  for (int mt = 0; mt < 2; ++mt) {
    float inv = 1.f / l_i[mt];
    int s = q0 + wave * 32 + mt * 16 + ln;
    size_t rowbase = ((size_t)b * SEQ + s) * (NH * VD) + h * VD;
#pragma unroll
    for (int dt = 0; dt < 8; ++dt) {
      ushort4 pk;
      pk.x = f2bf(o[mt][dt][0] * inv);
      pk.y = f2bf(o[mt][dt][1] * inv);
      pk.z = f2bf(o[mt][dt][2] * inv);
      pk.w = f2bf(o[mt][dt][3] * inv);
      *(ushort4*)&O[rowbase + dt * 16 + quad * 4] = pk;
    }
  }
}

extern "C" void kernel_launch(void* const* d_in, const int* in_sizes, int n_in,
                              void* d_out, int out_size, void* d_ws, size_t ws_size,
                              hipStream_t stream) {
  const float* x_f    = (const float*)d_in[0];
  const float* qaw_f  = (const float*)d_in[1];
  const float* qbw_f  = (const float*)d_in[2];
  const float* kvaw_f = (const float*)d_in[3];
  const float* kvbw_f = (const float*)d_in[4];
  const float* ow_f   = (const float*)d_in[5];

  char* ws = (char*)d_ws;
  size_t off = 0;
  auto alloc = [&](size_t n) {
    unsigned short* p = (unsigned short*)(ws + off);
    off = (off + n * 2 + 255) & ~(size_t)255;
    return p;
  };
  unsigned short* Xb    = alloc((size_t)BS * EMB);
  unsigned short* Wcomb = alloc((size_t)NCOMB * EMB);
  unsigned short* Wqb   = alloc((size_t)(NH * QKD) * QRANK);
  unsigned short* Wkvb  = alloc((size_t)(NH * 192) * KVRANK);
  unsigned short* Wo    = alloc((size_t)EMB * (NH * VD));
  unsigned short* CQKV  = alloc((size_t)BS * NCOMB);
  unsigned short* KVB   = alloc((size_t)BS * (NH * 192));
  unsigned short* Qry   = alloc((size_t)BHD * SEQ * QKD);
  unsigned short* Key   = alloc((size_t)BHD * SEQ * QKD);
  unsigned short* Vt    = alloc((size_t)BHD * VD * SEQ);
  unsigned short* AO    = alloc((size_t)BS * (NH * VD));

  cast_all<<<dim3(8192), 256, 0, stream>>>(x_f, qaw_f, kvaw_f, qbw_f, kvbw_f, ow_f,
                                           Xb, Wcomb, Wqb, Wkvb, Wo);

  // [cq | ckv] = x @ [q_a_w; kv_a_w]^T  (4096 x 2112, K=2048)
  gemm_bt<0><<<dim3((NCOMB + 127) / 128, BS / 128), 256, 0, stream>>>(
      Xb, EMB, Wcomb, EMB, CQKV, BS, NCOMB, EMB);
  // q = cq @ q_b_w^T with fused RoPE + permuted store (4096 x 2048, K=1536)
  gemm_q_rope<<<dim3((NH * QKD) / 128, BS / 128), 256, 0, stream>>>(
      CQKV, NCOMB, Wqb, QRANK, Qry, QRANK);
  // kvb = ckv @ kv_b_w^T (4096 x 3072, K=512)
  gemm_bt<0><<<dim3((NH * 192) / 128, BS / 128), 256, 0, stream>>>(
      CQKV + QRANK, NCOMB, Wkvb, KVRANK, KVB, BS, NH * 192, KVRANK);

  prep_key<<<dim3(BS), 256, 0, stream>>>(KVB, CQKV, Key);
  transpose_v<<<dim3(BHD * (SEQ / 64)), 256, 0, stream>>>(KVB, Vt);

  flash_attn<<<dim3(BHD, SEQ / 128), 256, 0, stream>>>(Qry, Key, Vt, AO);

  // out = AO @ o_w^T (fp32 out)
  gemm_bt<1><<<dim3(EMB / 128, BS / 128), 256, 0, stream>>>(
      AO, NH * VD, Wo, NH * VD, d_out, BS, EMB, NH * VD);
}